// Round 4
// baseline (2164.508 us; speedup 1.0000x reference)
//
#include <hip/hip_runtime.h>
#include <hip/hip_bf16.h>
#include <cstdint>
#include <cstddef>

// ---------- types / helpers ----------
typedef __attribute__((ext_vector_type(8))) short short8;   // 8 x bf16 (4 VGPRs)
typedef __attribute__((ext_vector_type(4))) float floatx4;  // mfma accumulator

__device__ inline float bf2f(unsigned short u) {
  union { unsigned int i; float f; } v; v.i = ((unsigned int)u) << 16; return v.f;
}
__device__ inline unsigned short f2bf(float f) {
  union { float f; unsigned int i; } v; v.f = f;
  unsigned int u = v.i;
  return (unsigned short)((u + 0x7FFFu + ((u >> 16) & 1u)) >> 16); // RNE
}
__device__ inline short8 ld8(const unsigned short* p) {
  return *reinterpret_cast<const short8*>(p); // 16B aligned everywhere we use it
}
__device__ inline float sigmoidf_(float x) { return 1.0f / (1.0f + expf(-x)); }

// ---------- workspace layout (bytes) — total ~28.4 MB ----------
static const size_t OFF_WIH   = 0;          // 2,097,152  bf16 w_ih (2048,512)
static const size_t OFF_WHH   = 2097152;    // 2,097,152  bf16 w_hh (2048,512)
static const size_t OFF_VPROJ = 4194304;    // 1,048,576  bf16 (1024,512)
static const size_t OFF_VISE  = 5242880;    //   524,288  bf16 (1024,256)
static const size_t OFF_HS    = 5767168;    // 1,310,720  bf16 (1280,512) row=b*20+t
static const size_t OFF_XIN   = 7077888;    //    65,536  bf16 (64,512)
static const size_t OFF_H0    = 7143424;    //    65,536  bf16 (64,512)
static const size_t OFF_H1    = 7208960;    //    65,536  bf16 (64,512)
static const size_t OFF_CT    = 7274496;    //   131,072  f32  (512,64)
static const size_t OFF_W1PAD = 7405568;    //     4,096  bf16 (64,32)
static const size_t OFF_CW2   = 7409664;    //   147,456  bf16 (128,576)
static const size_t OFF_CW3   = 7557120;    //   589,824  bf16 (256,1152)
static const size_t OFF_CW4   = 8146944;    // 2,359,296  bf16 (512,2304)
static const size_t OFF_PRJW  = 10506240;   //   262,144  bf16 (256,512)
static const size_t OFF_ATWV  = 10768384;   //   262,144  bf16 (512,256)
static const size_t OFF_ACT1  = 11030528;   // 8,388,608  bf16 (64,64,32,32); act3 reuses
static const size_t OFF_ACT3  = 11030528;   // 2,097,152  bf16 (64,256,8,8)
static const size_t OFF_ACT2  = 19419136;   // 4,194,304  bf16 (64,128,16,16); act4+visA reuse
static const size_t OFF_ACT4  = 19419136;   // 1,048,576  bf16 (64,512,4,4)
static const size_t OFF_VISA  = 20467712;   // 1,048,576  bf16 (1024,512)
static const size_t OFF_COL   = 23613440;   // 4,718,592  im2col arena; later out_w bf16 chunks

// ---------- f32 -> bf16 bulk convert (4 elems/thread) ----------
__global__ void cvt_k(const float* __restrict__ s, unsigned short* __restrict__ d, int n4)
{
  int i = blockIdx.x * 256 + threadIdx.x;
  if (i < n4) {
    float4 v = reinterpret_cast<const float4*>(s)[i];
    ushort4 o;
    o.x = f2bf(v.x); o.y = f2bf(v.y); o.z = f2bf(v.z); o.w = f2bf(v.w);
    reinterpret_cast<ushort4*>(d)[i] = o;
  }
}

// ---------- init: conv1 weight K-pad (f32->bf16), zero h0 / c ----------
__global__ void init_k(const float* __restrict__ conv1_w, unsigned short* __restrict__ w1pad,
                       unsigned short* __restrict__ h0, float* __restrict__ cT)
{
  int i = blockIdx.x * 256 + threadIdx.x;               // grid covers 32768
  if (i < 64 * 32) {
    int co = i >> 5, k = i & 31;
    w1pad[i] = (k < 27) ? f2bf(conv1_w[co * 27 + k]) : (unsigned short)0;
  }
  if (i < 64 * 512) h0[i] = 0;
  if (i < 512 * 64) cT[i] = 0.0f;
}

// ---------- im2col (chunked): col[local n][k] bf16; global n = n0 + blockIdx.x ----------
// n=(b,y,x), k=(ci,ky,kx), stride2 pad1. F32SRC: input is f32 (conv1), else bf16.
template<bool F32SRC>
__global__ void im2col_k(const void* __restrict__ in_, unsigned short* __restrict__ col,
                         int Cin, int Hin, int Win, int Kreal, int Kpad, int lgHW, int lgW,
                         int n0)
{
  const float* inf = (const float*)in_;
  const unsigned short* inb = (const unsigned short*)in_;
  const int ng = n0 + blockIdx.x;
  const int b = ng >> lgHW;
  const int yx = ng & ((1 << lgHW) - 1);
  const int y = yx >> lgW;
  const int x = yx & ((1 << lgW) - 1);
  const int iy0 = 2 * y - 1;
  const int ix0 = 2 * x - 1;
  for (int k = threadIdx.x; k < Kpad; k += blockDim.x) {
    unsigned short v = 0;
    if (k < Kreal) {
      int ci = k / 9;
      int r9 = k - ci * 9;
      int ky = r9 / 3;
      int kx = r9 - ky * 3;
      int iy = iy0 + ky, ix = ix0 + kx;
      if (iy >= 0 && iy < Hin && ix >= 0 && ix < Win) {
        size_t idx = (((size_t)b * Cin + ci) * Hin + iy) * Win + ix;
        v = F32SRC ? f2bf(inf[idx]) : inb[idx];
      }
    }
    col[(size_t)blockIdx.x * Kpad + k] = v;
  }
}

// ---------- gather visual: visA[(b*16+r)*512+c] = act4[b][c][r] ----------
__global__ void visa_k(const unsigned short* __restrict__ act4, unsigned short* __restrict__ visA)
{
  int o = blockIdx.x * 256 + threadIdx.x;   // 524288 total
  int c = o & 511, br = o >> 9;
  int b = br >> 4, r = br & 15;
  visA[o] = act4[(((size_t)b * 512 + c) << 4) + r];
}

// ---------- generic MFMA GEMM: C(M,N) = A(M,K) * B(N,K)^T, A/B bf16 ----------
// EPI 0: conv epilogue  relu(C*scale[m]+shift[m]) -> bf16 scatter (b,Cout,HW), n_base global
// EPI 1: bf16 out[m*N+n] = C + biasN[n]
// EPI 2: f32  out[m*ldOut + n_base + n] = C + biasN[n_base+n]
template<int EPI>
__global__ __launch_bounds__(256)
void gemm_k(const unsigned short* __restrict__ A, const unsigned short* __restrict__ B,
            int K, int N, void* __restrict__ outp,
            const float* __restrict__ cb, const float* __restrict__ bg,
            const float* __restrict__ bb, const float* __restrict__ bm,
            const float* __restrict__ bv, int Cout, int lgHW,
            const float* __restrict__ biasN, int n_base, int ldOut)
{
  const int w   = threadIdx.x >> 6;
  const int l   = threadIdx.x & 63;
  const int l15 = l & 15;
  const int q   = l >> 4;
  const int m0  = blockIdx.y * 64;
  const int n0  = blockIdx.x * 256 + w * 64;
  const unsigned short* Ap = A + (size_t)(m0 + l15) * K + q * 8;
  const unsigned short* Bp = B + (size_t)(n0 + l15) * K + q * 8;

  floatx4 acc[4][4];
  #pragma unroll
  for (int i = 0; i < 4; i++)
    #pragma unroll
    for (int j = 0; j < 4; j++)
      acc[i][j] = (floatx4){0.f, 0.f, 0.f, 0.f};

  for (int kc = 0; kc < K; kc += 32) {
    short8 a0 = ld8(Ap + kc);
    short8 a1 = ld8(Ap + (size_t)16 * K + kc);
    short8 a2 = ld8(Ap + (size_t)32 * K + kc);
    short8 a3 = ld8(Ap + (size_t)48 * K + kc);
    #pragma unroll
    for (int nf = 0; nf < 4; nf++) {
      short8 bf = ld8(Bp + (size_t)(nf * 16) * K + kc);
      acc[0][nf] = __builtin_amdgcn_mfma_f32_16x16x32_bf16(a0, bf, acc[0][nf], 0, 0, 0);
      acc[1][nf] = __builtin_amdgcn_mfma_f32_16x16x32_bf16(a1, bf, acc[1][nf], 0, 0, 0);
      acc[2][nf] = __builtin_amdgcn_mfma_f32_16x16x32_bf16(a2, bf, acc[2][nf], 0, 0, 0);
      acc[3][nf] = __builtin_amdgcn_mfma_f32_16x16x32_bf16(a3, bf, acc[3][nf], 0, 0, 0);
    }
  }
  // C/D layout (verified m89/m91): col = lane&15, row = (lane>>4)*4 + reg
  #pragma unroll
  for (int mf = 0; mf < 4; mf++) {
    #pragma unroll
    for (int r = 0; r < 4; r++) {
      int m = m0 + mf * 16 + q * 4 + r;
      float scale = 1.0f, shift = 0.0f;
      if (EPI == 0) {
        float inv = bg[m] / sqrtf(bv[m] + 1e-5f);
        scale = inv;
        shift = (cb[m] - bm[m]) * inv + bb[m];
      }
      #pragma unroll
      for (int nf = 0; nf < 4; nf++) {
        int n = n0 + nf * 16 + l15;
        float c = acc[mf][nf][r];
        if (EPI == 0) {
          c = fmaxf(c * scale + shift, 0.0f);
          int ng = n_base + n;
          int bi = ng >> lgHW;
          int yx = ng & ((1 << lgHW) - 1);
          ((unsigned short*)outp)[(((size_t)bi * Cout + m) << lgHW) + yx] = f2bf(c);
        } else if (EPI == 1) {
          ((unsigned short*)outp)[(size_t)m * N + n] = f2bf(c + biasN[n]);
        } else {
          ((float*)outp)[(size_t)m * ldOut + n_base + n] = c + biasN[n_base + n];
        }
      }
    }
  }
}

// ---------- attention (one block per batch) ----------
__global__ __launch_bounds__(256)
void attn_k(const unsigned short* __restrict__ h_in, const unsigned short* __restrict__ vproj,
            const unsigned short* __restrict__ visE, const float* __restrict__ att_wt,
            const float* __restrict__ att_bt, const float* __restrict__ att_wa,
            const float* __restrict__ att_ba, const int* __restrict__ captions,
            const float* __restrict__ emb, unsigned short* __restrict__ xin, int t)
{
  __shared__ __align__(16) float sH[512];
  __shared__ float sT[512];
  __shared__ float sSc[16];
  __shared__ float sAw[16];
  const int b = blockIdx.x;
  const int tid = threadIdx.x;

  for (int i = tid; i < 512; i += 256) sH[i] = bf2f(h_in[b * 512 + i]);
  __syncthreads();

  // tvec = att_wt @ h + att_bt   (f32 weights direct from d_in)
  for (int j = tid; j < 512; j += 256) {
    const float* wr = att_wt + (size_t)j * 512;
    float acc = 0.0f;
    #pragma unroll 4
    for (int k = 0; k < 512; k += 4) {
      float4 wv = *reinterpret_cast<const float4*>(wr + k);
      acc += wv.x * sH[k] + wv.y * sH[k + 1] + wv.z * sH[k + 2] + wv.w * sH[k + 3];
    }
    sT[j] = acc + att_bt[j];
  }
  __syncthreads();

  // scores: 16 threads per region, 32 k each
  {
    int r = tid >> 4, l16 = tid & 15;
    const unsigned short* vp = vproj + ((size_t)b * 16 + r) * 512;
    float s = 0.0f;
    int k0 = l16 * 32;
    for (int k = k0; k < k0 + 32; k++)
      s += tanhf(bf2f(vp[k]) + sT[k]) * att_wa[k];
    for (int d = 8; d >= 1; d >>= 1) s += __shfl_down(s, d, 16);
    if (l16 == 0) sSc[r] = s + att_ba[0];
  }
  __syncthreads();

  if (tid < 16) {
    float s = sSc[tid];
    float m = s;
    for (int d = 8; d >= 1; d >>= 1) m = fmaxf(m, __shfl_xor(m, d, 16));
    float e = expf(s - m);
    float sum = e;
    for (int d = 8; d >= 1; d >>= 1) sum += __shfl_xor(sum, d, 16);
    sAw[tid] = e / sum;
  }
  __syncthreads();

  {
    int e = tid; // 0..255
    float a = 0.0f;
    #pragma unroll
    for (int r = 0; r < 16; r++)
      a += sAw[r] * bf2f(visE[((size_t)b * 16 + r) * 256 + e]);
    int cap = captions[b * 20 + t];
    xin[b * 512 + e] = f2bf(emb[(size_t)cap * 256 + e]);  // word embedding (f32 src)
    xin[b * 512 + 256 + e] = f2bf(a);                     // attended
  }
}

// ---------- LSTM gates (MFMA GEMM M=2048,N=64,K=512+512) + cell ----------
// block bid: units [bid*16, bid*16+16); wave w = gate w (i,f,g,o). w_ih/w_hh are (2048,512) bf16.
__global__ __launch_bounds__(256)
void lstm_k(const unsigned short* __restrict__ w_ih, const unsigned short* __restrict__ w_hh,
            const float* __restrict__ b_ih, const float* __restrict__ b_hh,
            const unsigned short* __restrict__ xin, const unsigned short* __restrict__ h_in,
            unsigned short* __restrict__ h_out, float* __restrict__ cT,
            unsigned short* __restrict__ hs, int t)
{
  __shared__ float sG[4][16][64];  // [gate][unit-in-block][batch]
  const int u0  = blockIdx.x * 16;
  const int w   = threadIdx.x >> 6;
  const int l   = threadIdx.x & 63;
  const int l15 = l & 15;
  const int q   = l >> 4;
  const int arow = w * 512 + u0 + l15;                  // 0..2047
  const unsigned short* Ai = w_ih + (size_t)arow * 512 + q * 8;
  const unsigned short* Ah = w_hh + (size_t)arow * 512 + q * 8;
  const unsigned short* Bx = xin  + (size_t)l15 * 512 + q * 8;
  const unsigned short* Bh = h_in + (size_t)l15 * 512 + q * 8;

  floatx4 acc[4];
  #pragma unroll
  for (int nt = 0; nt < 4; nt++) acc[nt] = (floatx4){0.f, 0.f, 0.f, 0.f};

  for (int kc = 0; kc < 512; kc += 32) {
    short8 a = ld8(Ai + kc);
    #pragma unroll
    for (int nt = 0; nt < 4; nt++) {
      short8 bf = ld8(Bx + (size_t)(nt * 16) * 512 + kc);
      acc[nt] = __builtin_amdgcn_mfma_f32_16x16x32_bf16(a, bf, acc[nt], 0, 0, 0);
    }
    a = ld8(Ah + kc);
    #pragma unroll
    for (int nt = 0; nt < 4; nt++) {
      short8 bf = ld8(Bh + (size_t)(nt * 16) * 512 + kc);
      acc[nt] = __builtin_amdgcn_mfma_f32_16x16x32_bf16(a, bf, acc[nt], 0, 0, 0);
    }
  }
  #pragma unroll
  for (int nt = 0; nt < 4; nt++)
    #pragma unroll
    for (int r = 0; r < 4; r++)
      sG[w][q * 4 + r][nt * 16 + l15] = acc[nt][r];
  __syncthreads();

  const int batch = threadIdx.x & 63;
  const int g0 = threadIdx.x >> 6;
  #pragma unroll
  for (int s = 0; s < 4; s++) {
    int um = g0 * 4 + s;     // 0..15
    int u = u0 + um;
    float ii = sG[0][um][batch] + b_ih[u]        + b_hh[u];
    float ff = sG[1][um][batch] + b_ih[512 + u]  + b_hh[512 + u];
    float gg = sG[2][um][batch] + b_ih[1024 + u] + b_hh[1024 + u];
    float oo = sG[3][um][batch] + b_ih[1536 + u] + b_hh[1536 + u];
    float co = cT[u * 64 + batch];
    float cn = sigmoidf_(ff) * co + sigmoidf_(ii) * tanhf(gg);
    float hn = sigmoidf_(oo) * tanhf(cn);
    cT[u * 64 + batch] = cn;
    unsigned short hb = f2bf(hn);
    h_out[(size_t)batch * 512 + u] = hb;
    hs[((size_t)batch * 20 + t) * 512 + u] = hb;
  }
}

// ---------- launch ----------
extern "C" void kernel_launch(void* const* d_in, const int* in_sizes, int n_in,
                              void* d_out, int out_size, void* d_ws, size_t ws_size,
                              hipStream_t stream)
{
  const float* images   = (const float*)d_in[0];
  const int*   captions = (const int*)d_in[1];
  const float* cw[4] = {(const float*)d_in[2],  (const float*)d_in[8],
                        (const float*)d_in[14], (const float*)d_in[20]};
  const float* cbp[4] = {(const float*)d_in[3],  (const float*)d_in[9],
                         (const float*)d_in[15], (const float*)d_in[21]};
  const float* bgp[4] = {(const float*)d_in[4],  (const float*)d_in[10],
                         (const float*)d_in[16], (const float*)d_in[22]};
  const float* bbp[4] = {(const float*)d_in[5],  (const float*)d_in[11],
                         (const float*)d_in[17], (const float*)d_in[23]};
  const float* bmp[4] = {(const float*)d_in[6],  (const float*)d_in[12],
                         (const float*)d_in[18], (const float*)d_in[24]};
  const float* bvp[4] = {(const float*)d_in[7],  (const float*)d_in[13],
                         (const float*)d_in[19], (const float*)d_in[25]};
  const float* proj_w = (const float*)d_in[26];
  const float* proj_b = (const float*)d_in[27];
  const float* emb    = (const float*)d_in[28];
  const float* att_wv = (const float*)d_in[29];
  const float* att_bv = (const float*)d_in[30];
  const float* att_wt = (const float*)d_in[31];
  const float* att_bt = (const float*)d_in[32];
  const float* att_wa = (const float*)d_in[33];
  const float* att_ba = (const float*)d_in[34];
  const float* w_ih   = (const float*)d_in[35];
  const float* w_hh   = (const float*)d_in[36];
  const float* b_ih   = (const float*)d_in[37];
  const float* b_hh   = (const float*)d_in[38];
  const float* out_w  = (const float*)d_in[39];
  const float* out_b  = (const float*)d_in[40];

  char* W = (char*)d_ws;
  unsigned short* wih_b = (unsigned short*)(W + OFF_WIH);
  unsigned short* whh_b = (unsigned short*)(W + OFF_WHH);
  unsigned short* vproj = (unsigned short*)(W + OFF_VPROJ);
  unsigned short* visE  = (unsigned short*)(W + OFF_VISE);
  unsigned short* hs    = (unsigned short*)(W + OFF_HS);
  unsigned short* xin   = (unsigned short*)(W + OFF_XIN);
  unsigned short* h0    = (unsigned short*)(W + OFF_H0);
  unsigned short* h1    = (unsigned short*)(W + OFF_H1);
  float*          cT    = (float*)(W + OFF_CT);
  unsigned short* w1pad = (unsigned short*)(W + OFF_W1PAD);
  unsigned short* cw2_b = (unsigned short*)(W + OFF_CW2);
  unsigned short* cw3_b = (unsigned short*)(W + OFF_CW3);
  unsigned short* cw4_b = (unsigned short*)(W + OFF_CW4);
  unsigned short* prw_b = (unsigned short*)(W + OFF_PRJW);
  unsigned short* awv_b = (unsigned short*)(W + OFF_ATWV);
  unsigned short* act1  = (unsigned short*)(W + OFF_ACT1);
  unsigned short* act2  = (unsigned short*)(W + OFF_ACT2);
  unsigned short* act3  = (unsigned short*)(W + OFF_ACT3);
  unsigned short* act4  = (unsigned short*)(W + OFF_ACT4);
  unsigned short* visA  = (unsigned short*)(W + OFF_VISA);
  unsigned short* col   = (unsigned short*)(W + OFF_COL);

  init_k<<<128, 256, 0, stream>>>(cw[0], w1pad, h0, cT);
  // weight conversions f32 -> bf16 (count = elems/4)
  cvt_k<<<1024, 256, 0, stream>>>(w_ih,  wih_b, 2048 * 512 / 4);   // (2048,512)!
  cvt_k<<<1024, 256, 0, stream>>>(w_hh,  whh_b, 2048 * 512 / 4);
  cvt_k<<<72,   256, 0, stream>>>(cw[1], cw2_b, 128 * 576 / 4);
  cvt_k<<<288,  256, 0, stream>>>(cw[2], cw3_b, 256 * 1152 / 4);
  cvt_k<<<1152, 256, 0, stream>>>(cw[3], cw4_b, 512 * 2304 / 4);
  cvt_k<<<128,  256, 0, stream>>>(proj_w, prw_b, 256 * 512 / 4);
  cvt_k<<<128,  256, 0, stream>>>(att_wv, awv_b, 512 * 256 / 4);

  // conv1: (64,3,64,64) -> (64,64,32,32)
  im2col_k<true><<<65536, 64, 0, stream>>>(images, col, 3, 64, 64, 27, 32, 10, 5, 0);
  gemm_k<0><<<dim3(256, 1), 256, 0, stream>>>(w1pad, col, 32, 65536, act1,
      cbp[0], bgp[0], bbp[0], bmp[0], bvp[0], 64, 10, nullptr, 0, 0);
  // conv2: -> (64,128,16,16); 4 chunks
  for (int c = 0; c < 4; c++) {
    im2col_k<false><<<4096, 256, 0, stream>>>(act1, col, 64, 32, 32, 576, 576, 8, 4, c * 4096);
    gemm_k<0><<<dim3(16, 2), 256, 0, stream>>>(cw2_b, col, 576, 4096, act2,
        cbp[1], bgp[1], bbp[1], bmp[1], bvp[1], 128, 8, nullptr, c * 4096, 0);
  }
  // conv3: -> (64,256,8,8); 2 chunks (act3 overlays act1)
  for (int c = 0; c < 2; c++) {
    im2col_k<false><<<2048, 256, 0, stream>>>(act2, col, 128, 16, 16, 1152, 1152, 6, 3, c * 2048);
    gemm_k<0><<<dim3(8, 4), 256, 0, stream>>>(cw3_b, col, 1152, 2048, act3,
        cbp[2], bgp[2], bbp[2], bmp[2], bvp[2], 256, 6, nullptr, c * 2048, 0);
  }
  // conv4: -> (64,512,4,4); act4 overlays act2
  im2col_k<false><<<1024, 256, 0, stream>>>(act3, col, 256, 8, 8, 2304, 2304, 4, 2, 0);
  gemm_k<0><<<dim3(4, 8), 256, 0, stream>>>(cw4_b, col, 2304, 1024, act4,
      cbp[3], bgp[3], bbp[3], bmp[3], bvp[3], 512, 4, nullptr, 0, 0);

  // visual gather + projections
  visa_k<<<2048, 256, 0, stream>>>(act4, visA);
  gemm_k<1><<<dim3(1, 16), 256, 0, stream>>>(visA, prw_b, 512, 256, visE,
      nullptr, nullptr, nullptr, nullptr, nullptr, 0, 0, proj_b, 0, 0);
  gemm_k<1><<<dim3(2, 16), 256, 0, stream>>>(visE, awv_b, 256, 512, vproj,
      nullptr, nullptr, nullptr, nullptr, nullptr, 0, 0, att_bv, 0, 0);

  // recurrence
  for (int t = 0; t < 20; t++) {
    unsigned short* hin  = (t & 1) ? h1 : h0;
    unsigned short* hout = (t & 1) ? h0 : h1;
    attn_k<<<64, 256, 0, stream>>>(hin, vproj, visE, att_wt, att_bt, att_wa, att_ba,
                                   captions, emb, xin, t);
    lstm_k<<<32, 256, 0, stream>>>(wih_b, whh_b, b_ih, b_hh, xin, hin, hout, cT, hs, t);
  }

  // logits: (1280,512) x (32000,512)^T -> d_out f32 (B,T,V); out_w converted in chunks
  for (int c = 0; c < 8; c++) {
    int rows = (c < 7) ? 4096 : 3328;
    const float* src = out_w + (size_t)c * 4096 * 512;
    cvt_k<<<rows / 2, 256, 0, stream>>>(src, col, rows * 512 / 4);
    gemm_k<2><<<dim3(rows / 256, 20), 256, 0, stream>>>(hs, col, 512, rows,
        d_out, nullptr, nullptr, nullptr, nullptr, nullptr, 0, 0, out_b, c * 4096, 32000);
  }
}